// Round 6
// baseline (255.351 us; speedup 1.0000x reference)
//
#include <hip/hip_runtime.h>
#include <math.h>

#define D_MODEL 1024
#define NHEAD 16
#define HD 64
#define SEQ 2048
#define BATCH 2
#define MTOT (BATCH * SEQ)  // 4096

typedef __attribute__((ext_vector_type(8))) short bf16x8;
typedef __attribute__((ext_vector_type(4))) float f32x4;

__device__ __forceinline__ unsigned short f2bf(float f) {
    unsigned int u = __float_as_uint(f);
    u += 0x7FFF + ((u >> 16) & 1);  // round-to-nearest-even
    return (unsigned short)(u >> 16);
}

__device__ __forceinline__ unsigned int pk2bf(float a, float b) {
    return (unsigned int)f2bf(a) | ((unsigned int)f2bf(b) << 16);
}

// async global->LDS, 16B per lane. lds must be the wave-uniform chunk base:
// HW writes lane's 16B to base + lane*16 (guide §5 caveat).
__device__ __forceinline__ void async16(unsigned short* lds, const unsigned short* g) {
    __builtin_amdgcn_global_load_lds(
        (const __attribute__((address_space(1))) unsigned int*)g,
        (__attribute__((address_space(3))) unsigned int*)lds, 16, 0, 0);
}

// ---------------------------------------------------------------------------
// x (fp32 [4096,1024]) -> bf16, same layout.
// ---------------------------------------------------------------------------
__global__ __launch_bounds__(256) void convert_x(const float* __restrict__ x,
                                                 unsigned short* __restrict__ xb) {
    const int i = (blockIdx.x * 256 + threadIdx.x) * 4;
    float4 v = *(const float4*)(x + i);
    uint2 p;
    p.x = pk2bf(v.x, v.y);
    p.y = pk2bf(v.z, v.w);
    *(uint2*)(xb + i) = p;
}

// ---------------------------------------------------------------------------
// W [1024(k),1024(n)] fp32 -> Wt [1024(n),1024(k)] bf16, all 4 weights.
// ---------------------------------------------------------------------------
__global__ __launch_bounds__(256) void transpose_w(const float* __restrict__ W0,
                                                   const float* __restrict__ W1,
                                                   const float* __restrict__ W2,
                                                   const float* __restrict__ W3,
                                                   unsigned short* __restrict__ Wt) {
    __shared__ float T[32][33];
    const float* W = (blockIdx.z == 0) ? W0 : (blockIdx.z == 1) ? W1
                    : (blockIdx.z == 2) ? W2 : W3;
    unsigned short* out = Wt + (size_t)blockIdx.z * D_MODEL * D_MODEL;
    const int n0 = blockIdx.x * 32, k0 = blockIdx.y * 32;
    const int tx = threadIdx.x, ty = threadIdx.y;
#pragma unroll
    for (int i = 0; i < 4; ++i)
        T[ty + 8 * i][tx] = W[(size_t)(k0 + ty + 8 * i) * D_MODEL + n0 + tx];
    __syncthreads();
#pragma unroll
    for (int i = 0; i < 4; ++i)
        out[(size_t)(n0 + ty + 8 * i) * D_MODEL + k0 + tx] = f2bf(T[tx][ty + 8 * i]);
}

// ---------------------------------------------------------------------------
// bf16 MFMA GEMM, global_load_lds staging (width=16, unpadded LDS).
// 128x128 tile / block, BK=64, 256 threads = 4 waves (2x2), each wave 64x64.
// MODE 0: z selects Wq/Wk/Wv; writes Q (pre-scaled by 0.125*log2e), K ->
//         [B,H,N,64] and V -> V^T [B,H,64,N] via LDS-staged coalesced stores.
// MODE 1: fp32 row-major output.
// ---------------------------------------------------------------------------
template <int MODE>
__global__ __launch_bounds__(256) void gemm_mfma(const unsigned short* __restrict__ A,
                                                 const unsigned short* __restrict__ Wt,
                                                 unsigned short* __restrict__ q,
                                                 unsigned short* __restrict__ k,
                                                 unsigned short* __restrict__ vt,
                                                 float* __restrict__ outf) {
    __shared__ unsigned short SM[16384];  // As = SM[0:8192), Bs = SM[8192:16384)
    const int tid = threadIdx.x;
    const int z = blockIdx.z;
    const unsigned short* B = Wt + (size_t)z * D_MODEL * D_MODEL;
    const int m0 = blockIdx.y * 128, n0 = blockIdx.x * 128;
    const int wave = tid >> 6, lane = tid & 63;
    const int quad = lane >> 4, l16 = lane & 15;
    const int wm = wave & 1, wn = wave >> 1;

    f32x4 acc[4][4];
#pragma unroll
    for (int mt = 0; mt < 4; ++mt)
#pragma unroll
        for (int nt = 0; nt < 4; ++nt)
            acc[mt][nt] = (f32x4){0.f, 0.f, 0.f, 0.f};

    for (int k0 = 0; k0 < D_MODEL; k0 += 64) {
        __syncthreads();  // previous iteration's reads done
#pragma unroll
        for (int i = 0; i < 4; ++i) {
            const int c = i * 256 + tid;
            const int r = c >> 3, cc = (c & 7) * 8;
            const int cbase = i * 256 + wave * 64;  // wave-uniform chunk base
            async16(SM + cbase * 8, A + (size_t)(m0 + r) * D_MODEL + k0 + cc);
            async16(SM + 8192 + cbase * 8, B + (size_t)(n0 + r) * D_MODEL + k0 + cc);
        }
        __syncthreads();  // drains vmcnt per barrier semantics
#pragma unroll
        for (int ks = 0; ks < 2; ++ks) {
            bf16x8 af[4], bfr[4];
#pragma unroll
            for (int mt = 0; mt < 4; ++mt)
                af[mt] = *(const bf16x8*)&SM[(wm * 64 + mt * 16 + l16) * 64 + ks * 32 + quad * 8];
#pragma unroll
            for (int nt = 0; nt < 4; ++nt)
                bfr[nt] = *(const bf16x8*)&SM[8192 + (wn * 64 + nt * 16 + l16) * 64 + ks * 32 + quad * 8];
#pragma unroll
            for (int mt = 0; mt < 4; ++mt)
#pragma unroll
                for (int nt = 0; nt < 4; ++nt)
                    acc[mt][nt] = __builtin_amdgcn_mfma_f32_16x16x32_bf16(
                        af[mt], bfr[nt], acc[mt][nt], 0, 0, 0);
        }
    }

    if (MODE == 1) {
#pragma unroll
        for (int mt = 0; mt < 4; ++mt)
#pragma unroll
            for (int nt = 0; nt < 4; ++nt)
#pragma unroll
                for (int reg = 0; reg < 4; ++reg) {
                    const int m = m0 + wm * 64 + mt * 16 + quad * 4 + reg;
                    const int n = n0 + wn * 64 + nt * 16 + l16;
                    outf[(size_t)m * D_MODEL + n] = acc[mt][nt][reg];
                }
    } else if (z < 2) {
        // Q gets the softmax scale folded in (exp2 domain): 0.125 * log2(e)
        const float qsc = (z == 0) ? 0.18033688011112042f : 1.0f;
        unsigned short* dst = (z == 0) ? q : k;
#pragma unroll
        for (int mt = 0; mt < 4; ++mt)
#pragma unroll
            for (int nt = 0; nt < 4; ++nt)
#pragma unroll
                for (int reg = 0; reg < 4; ++reg) {
                    const int m = m0 + wm * 64 + mt * 16 + quad * 4 + reg;
                    const int n = n0 + wn * 64 + nt * 16 + l16;
                    const int bb = m >> 11, tok = m & (SEQ - 1);
                    const int h = n >> 6, d = n & (HD - 1);
                    dst[(((size_t)bb * NHEAD + h) * SEQ + tok) * HD + d] =
                        f2bf(acc[mt][nt][reg] * qsc);
                }
    } else {
        // V^T epilogue: stage [d][m] in LDS (pad 136), then coalesced stores.
        const int bb = m0 >> 11, tok0 = m0 & (SEQ - 1);
#pragma unroll
        for (int pass = 0; pass < 2; ++pass) {
            __syncthreads();  // SM free (K-loop or previous pass done)
            if (wn == pass) {
#pragma unroll
                for (int mt = 0; mt < 4; ++mt)
#pragma unroll
                    for (int nt = 0; nt < 4; ++nt) {
                        const int d = nt * 16 + l16;
                        const int m = wm * 64 + mt * 16 + quad * 4;
                        uint2 w;
                        w.x = pk2bf(acc[mt][nt][0], acc[mt][nt][1]);
                        w.y = pk2bf(acc[mt][nt][2], acc[mt][nt][3]);
                        *(uint2*)&SM[d * 136 + m] = w;
                    }
            }
            __syncthreads();
            const int h = (n0 >> 6) + pass;
#pragma unroll
            for (int it = 0; it < 4; ++it) {
                const int c = it * 256 + tid;
                const int d = c >> 4, mc = (c & 15) * 8;
                uint4 val = *(const uint4*)&SM[d * 136 + mc];
                *(uint4*)(vt + (((size_t)bb * NHEAD + h) * HD + d) * SEQ + tok0 + mc) = val;
            }
        }
    }
}

// ---------------------------------------------------------------------------
// Attention helpers
// ---------------------------------------------------------------------------
__device__ __forceinline__ void load_k(const unsigned short* __restrict__ Kp,
                                       int kt, int l16, int quad, bf16x8 aK[4][2]) {
#pragma unroll
    for (int mt = 0; mt < 4; ++mt)
#pragma unroll
        for (int ks = 0; ks < 2; ++ks)
            aK[mt][ks] = *(const bf16x8*)(Kp +
                (size_t)(kt * 64 + mt * 16 + l16) * HD + ks * 32 + quad * 8);
}

__device__ __forceinline__ void attn_step(int kt, int row0, int l16, int quad,
                                          const unsigned short* __restrict__ Vp,
                                          const bf16x8 aK[4][2], const bf16x8 bQ[2][2],
                                          f32x4 o[4][2], float* ps,
                                          unsigned short (*Pw)[72]) {
    // V fragments issued early, consumed at the end (self-hiding latency)
    bf16x8 aV[4][2];
#pragma unroll
    for (int nt = 0; nt < 4; ++nt)
#pragma unroll
        for (int ks = 0; ks < 2; ++ks)
            aV[nt][ks] = *(const bf16x8*)(Vp +
                (size_t)(nt * 16 + l16) * SEQ + kt * 64 + ks * 32 + quad * 8);

    // S^T = K Q^T  (Q pre-scaled by 0.125*log2e at projection)
    f32x4 sT[4][2];
#pragma unroll
    for (int mt = 0; mt < 4; ++mt)
#pragma unroll
        for (int f = 0; f < 2; ++f) {
            sT[mt][f] = __builtin_amdgcn_mfma_f32_16x16x32_bf16(
                aK[mt][0], bQ[f][0], (f32x4){0.f, 0.f, 0.f, 0.f}, 0, 0, 0);
            sT[mt][f] = __builtin_amdgcn_mfma_f32_16x16x32_bf16(
                aK[mt][1], bQ[f][1], sT[mt][f], 0, 0, 0);
        }

    // exp2 + causal mask + packed P write + row-sum accumulate
    const bool diag = (kt * 64 + 63 > row0);
#pragma unroll
    for (int mt = 0; mt < 4; ++mt)
#pragma unroll
        for (int f = 0; f < 2; ++f) {
            float p[4];
#pragma unroll
            for (int reg = 0; reg < 4; ++reg)
                p[reg] = exp2f(sT[mt][f][reg]);
            if (diag) {
                const int kb = kt * 64 + mt * 16 + quad * 4;
                const int qg = row0 + f * 16 + l16;
#pragma unroll
                for (int reg = 0; reg < 4; ++reg)
                    p[reg] = (kb + reg > qg) ? 0.f : p[reg];
            }
            ps[f] += (p[0] + p[1]) + (p[2] + p[3]);
            uint2 w;
            w.x = pk2bf(p[0], p[1]);
            w.y = pk2bf(p[2], p[3]);
            *(uint2*)&Pw[f * 16 + l16][mt * 16 + quad * 4] = w;
        }

    // P back in B-layout (wave-private LDS rows; same-wave DS program order)
    bf16x8 bP[2][2];
#pragma unroll
    for (int f = 0; f < 2; ++f)
#pragma unroll
        for (int ks = 0; ks < 2; ++ks)
            bP[f][ks] = *(const bf16x8*)&Pw[f * 16 + l16][ks * 32 + quad * 8];

    // O^T += V^T P^T
#pragma unroll
    for (int nt = 0; nt < 4; ++nt)
#pragma unroll
        for (int f = 0; f < 2; ++f) {
            o[nt][f] = __builtin_amdgcn_mfma_f32_16x16x32_bf16(
                aV[nt][0], bP[f][0], o[nt][f], 0, 0, 0);
            o[nt][f] = __builtin_amdgcn_mfma_f32_16x16x32_bf16(
                aV[nt][1], bP[f][1], o[nt][f], 0, 0, 0);
        }
}

// ---------------------------------------------------------------------------
// MFMA flash attention (causal), barrier-free, balanced, K-prefetched.
// Grid (32, NHEAD, BATCH), 128 threads = 2 waves.
// wave0 -> 32-row q-band blockIdx.x, wave1 -> band 63-blockIdx.x.
// Register ping-pong prefetch of next kt's K fragments hides L2 latency.
// ---------------------------------------------------------------------------
__global__ __launch_bounds__(128) void attn_mfma(const unsigned short* __restrict__ Q,
                                                 const unsigned short* __restrict__ K,
                                                 const unsigned short* __restrict__ VT,
                                                 unsigned short* __restrict__ ctx) {
    __shared__ unsigned short Pl[64][72];  // rows [w*32, w*32+32) private to wave w
    const int tid = threadIdx.x;
    const int wave = tid >> 6, lane = tid & 63;
    const int quad = lane >> 4, l16 = lane & 15;
    const int band = wave ? (63 - blockIdx.x) : blockIdx.x;
    const int h = blockIdx.y, b = blockIdx.z;
    const int row0 = band * 32;
    const unsigned short* Qp = Q + ((size_t)b * NHEAD + h) * SEQ * HD;
    const unsigned short* Kp = K + ((size_t)b * NHEAD + h) * SEQ * HD;
    const unsigned short* Vp = VT + ((size_t)b * NHEAD + h) * HD * SEQ;
    unsigned short (*Pw)[72] = (unsigned short (*)[72])&Pl[wave * 32];

    bf16x8 bQ[2][2];  // Q as B-operand: [q-frag][ks]
#pragma unroll
    for (int f = 0; f < 2; ++f)
#pragma unroll
        for (int ks = 0; ks < 2; ++ks)
            bQ[f][ks] = *(const bf16x8*)(Qp +
                (size_t)(row0 + f * 16 + l16) * HD + ks * 32 + quad * 8);

    f32x4 o[4][2];    // O^T accumulators: [d-tile][q-frag]
    float ps[2] = {0.f, 0.f};
#pragma unroll
    for (int nt = 0; nt < 4; ++nt)
#pragma unroll
        for (int f = 0; f < 2; ++f)
            o[nt][f] = (f32x4){0.f, 0.f, 0.f, 0.f};

    const int ktmax = row0 >> 6;

    bf16x8 aKa[4][2], aKb[4][2];
    load_k(Kp, 0, l16, quad, aKa);
    for (int kt = 0; kt <= ktmax; kt += 2) {
        const int kn1 = (kt + 1 <= ktmax) ? kt + 1 : ktmax;
        load_k(Kp, kn1, l16, quad, aKb);
        attn_step(kt, row0, l16, quad, Vp, aKa, bQ, o, ps, Pw);
        if (kt + 1 <= ktmax) {
            const int kn2 = (kt + 2 <= ktmax) ? kt + 2 : ktmax;
            load_k(Kp, kn2, l16, quad, aKa);
            attn_step(kt + 1, row0, l16, quad, Vp, aKb, bQ, o, ps, Pw);
        }
    }

    // row-sum reduce across quads (q-row lives in l16; partials in quads)
    float inv[2];
#pragma unroll
    for (int f = 0; f < 2; ++f) {
        ps[f] += __shfl_xor(ps[f], 16);
        ps[f] += __shfl_xor(ps[f], 32);
        inv[f] = 1.f / ps[f];
    }

    // ctx store: token = row0 + f*16 + l16; cols consecutive -> packed 8B
#pragma unroll
    for (int nt = 0; nt < 4; ++nt)
#pragma unroll
        for (int f = 0; f < 2; ++f) {
            const int tok = row0 + f * 16 + l16;
            const int col = h * HD + nt * 16 + quad * 4;
            uint2 w;
            w.x = pk2bf(o[nt][f][0] * inv[f], o[nt][f][1] * inv[f]);
            w.y = pk2bf(o[nt][f][2] * inv[f], o[nt][f][3] * inv[f]);
            *(uint2*)(ctx + ((size_t)b * SEQ + tok) * D_MODEL + col) = w;
        }
}

extern "C" void kernel_launch(void* const* d_in, const int* in_sizes, int n_in,
                              void* d_out, int out_size, void* d_ws, size_t ws_size,
                              hipStream_t stream) {
    const float* x  = (const float*)d_in[0];
    const float* Wq = (const float*)d_in[1];
    const float* Wk = (const float*)d_in[2];
    const float* Wv = (const float*)d_in[3];
    const float* Wo = (const float*)d_in[4];
    float* out = (float*)d_out;

    unsigned short* ws = (unsigned short*)d_ws;
    const size_t T = (size_t)MTOT * D_MODEL;  // 4,194,304 elements
    unsigned short* xb  = ws;                 // [4096,1024] bf16
    unsigned short* Wt  = ws + T;             // 4 x [1024,1024] bf16 (W^T)
    unsigned short* q   = ws + 2 * T;         // [B,H,N,64]  (pre-scaled)
    unsigned short* k   = ws + 3 * T;         // [B,H,N,64]
    unsigned short* vt  = ws + 4 * T;         // [B,H,64,N]
    unsigned short* ctx = ws + 5 * T;         // [4096,1024]

    convert_x<<<dim3(MTOT * D_MODEL / 1024), dim3(256), 0, stream>>>(x, xb);
    transpose_w<<<dim3(32, 32, 4), dim3(32, 8), 0, stream>>>(Wq, Wk, Wv, Wo, Wt);

    gemm_mfma<0><<<dim3(8, 32, 3), dim3(256), 0, stream>>>(xb, Wt, q, k, vt, nullptr);

    attn_mfma<<<dim3(32, NHEAD, BATCH), dim3(128), 0, stream>>>(q, k, vt, ctx);

    gemm_mfma<1><<<dim3(8, 32, 1), dim3(256), 0, stream>>>(ctx, Wt + 3 * (size_t)D_MODEL * D_MODEL,
                                                           nullptr, nullptr, nullptr, out);
}

// Round 7
// 230.157 us; speedup vs baseline: 1.1095x; 1.1095x over previous
//
#include <hip/hip_runtime.h>
#include <math.h>

#define D_MODEL 1024
#define NHEAD 16
#define HD 64
#define SEQ 2048
#define BATCH 2
#define MTOT (BATCH * SEQ)  // 4096

typedef __attribute__((ext_vector_type(8))) short bf16x8;
typedef __attribute__((ext_vector_type(4))) float f32x4;

__device__ __forceinline__ unsigned short f2bf(float f) {
    unsigned int u = __float_as_uint(f);
    u += 0x7FFF + ((u >> 16) & 1);  // round-to-nearest-even
    return (unsigned short)(u >> 16);
}

__device__ __forceinline__ unsigned int pk2bf(float a, float b) {
    return (unsigned int)f2bf(a) | ((unsigned int)f2bf(b) << 16);
}

// async global->LDS, 16B per lane. lds must be the wave-uniform chunk base:
// HW writes lane's 16B to base + lane*16 (guide §5 caveat).
__device__ __forceinline__ void async16(unsigned short* lds, const unsigned short* g) {
    __builtin_amdgcn_global_load_lds(
        (const __attribute__((address_space(1))) unsigned int*)g,
        (__attribute__((address_space(3))) unsigned int*)lds, 16, 0, 0);
}

// raw barrier: no compiler-forced vmcnt(0) drain (unlike __syncthreads);
// "memory" clobber = compile-time fence so LDS/DMA ops don't cross.
#define BAR() asm volatile("s_barrier" ::: "memory")

// ---------------------------------------------------------------------------
// x (fp32 [4096,1024]) -> bf16, same layout.
// ---------------------------------------------------------------------------
__global__ __launch_bounds__(256) void convert_x(const float* __restrict__ x,
                                                 unsigned short* __restrict__ xb) {
    const int i = (blockIdx.x * 256 + threadIdx.x) * 4;
    float4 v = *(const float4*)(x + i);
    uint2 p;
    p.x = pk2bf(v.x, v.y);
    p.y = pk2bf(v.z, v.w);
    *(uint2*)(xb + i) = p;
}

// ---------------------------------------------------------------------------
// W [1024(k),1024(n)] fp32 -> Wt [1024(n),1024(k)] bf16, all 4 weights.
// ---------------------------------------------------------------------------
__global__ __launch_bounds__(256) void transpose_w(const float* __restrict__ W0,
                                                   const float* __restrict__ W1,
                                                   const float* __restrict__ W2,
                                                   const float* __restrict__ W3,
                                                   unsigned short* __restrict__ Wt) {
    __shared__ float T[32][33];
    const float* W = (blockIdx.z == 0) ? W0 : (blockIdx.z == 1) ? W1
                    : (blockIdx.z == 2) ? W2 : W3;
    unsigned short* out = Wt + (size_t)blockIdx.z * D_MODEL * D_MODEL;
    const int n0 = blockIdx.x * 32, k0 = blockIdx.y * 32;
    const int tx = threadIdx.x, ty = threadIdx.y;
#pragma unroll
    for (int i = 0; i < 4; ++i)
        T[ty + 8 * i][tx] = W[(size_t)(k0 + ty + 8 * i) * D_MODEL + n0 + tx];
    __syncthreads();
#pragma unroll
    for (int i = 0; i < 4; ++i)
        out[(size_t)(n0 + ty + 8 * i) * D_MODEL + k0 + tx] = f2bf(T[tx][ty + 8 * i]);
}

// ---------------------------------------------------------------------------
// bf16 MFMA GEMM, global_load_lds staging (width=16, unpadded LDS).
// 128x128 tile / block, BK=64, 256 threads = 4 waves (2x2), each wave 64x64.
// MODE 0: z selects Wq/Wk/Wv; writes Q (pre-scaled by 0.125*log2e), K ->
//         [B,H,N,64] and V -> V^T [B,H,64,N] via LDS-staged coalesced stores.
// MODE 1: fp32 row-major output.
// ---------------------------------------------------------------------------
template <int MODE>
__global__ __launch_bounds__(256) void gemm_mfma(const unsigned short* __restrict__ A,
                                                 const unsigned short* __restrict__ Wt,
                                                 unsigned short* __restrict__ q,
                                                 unsigned short* __restrict__ k,
                                                 unsigned short* __restrict__ vt,
                                                 float* __restrict__ outf) {
    __shared__ unsigned short SM[16384];  // As = SM[0:8192), Bs = SM[8192:16384)
    const int tid = threadIdx.x;
    const int z = blockIdx.z;
    const unsigned short* B = Wt + (size_t)z * D_MODEL * D_MODEL;
    const int m0 = blockIdx.y * 128, n0 = blockIdx.x * 128;
    const int wave = tid >> 6, lane = tid & 63;
    const int quad = lane >> 4, l16 = lane & 15;
    const int wm = wave & 1, wn = wave >> 1;

    f32x4 acc[4][4];
#pragma unroll
    for (int mt = 0; mt < 4; ++mt)
#pragma unroll
        for (int nt = 0; nt < 4; ++nt)
            acc[mt][nt] = (f32x4){0.f, 0.f, 0.f, 0.f};

    for (int k0 = 0; k0 < D_MODEL; k0 += 64) {
        __syncthreads();  // previous iteration's reads done
#pragma unroll
        for (int i = 0; i < 4; ++i) {
            const int c = i * 256 + tid;
            const int r = c >> 3, cc = (c & 7) * 8;
            const int cbase = i * 256 + wave * 64;  // wave-uniform chunk base
            async16(SM + cbase * 8, A + (size_t)(m0 + r) * D_MODEL + k0 + cc);
            async16(SM + 8192 + cbase * 8, B + (size_t)(n0 + r) * D_MODEL + k0 + cc);
        }
        __syncthreads();  // drains vmcnt per barrier semantics
#pragma unroll
        for (int ks = 0; ks < 2; ++ks) {
            bf16x8 af[4], bfr[4];
#pragma unroll
            for (int mt = 0; mt < 4; ++mt)
                af[mt] = *(const bf16x8*)&SM[(wm * 64 + mt * 16 + l16) * 64 + ks * 32 + quad * 8];
#pragma unroll
            for (int nt = 0; nt < 4; ++nt)
                bfr[nt] = *(const bf16x8*)&SM[8192 + (wn * 64 + nt * 16 + l16) * 64 + ks * 32 + quad * 8];
#pragma unroll
            for (int mt = 0; mt < 4; ++mt)
#pragma unroll
                for (int nt = 0; nt < 4; ++nt)
                    acc[mt][nt] = __builtin_amdgcn_mfma_f32_16x16x32_bf16(
                        af[mt], bfr[nt], acc[mt][nt], 0, 0, 0);
        }
    }

    if (MODE == 1) {
#pragma unroll
        for (int mt = 0; mt < 4; ++mt)
#pragma unroll
            for (int nt = 0; nt < 4; ++nt)
#pragma unroll
                for (int reg = 0; reg < 4; ++reg) {
                    const int m = m0 + wm * 64 + mt * 16 + quad * 4 + reg;
                    const int n = n0 + wn * 64 + nt * 16 + l16;
                    outf[(size_t)m * D_MODEL + n] = acc[mt][nt][reg];
                }
    } else if (z < 2) {
        // Q gets the softmax scale folded in (exp2 domain): 0.125 * log2(e)
        const float qsc = (z == 0) ? 0.18033688011112042f : 1.0f;
        unsigned short* dst = (z == 0) ? q : k;
#pragma unroll
        for (int mt = 0; mt < 4; ++mt)
#pragma unroll
            for (int nt = 0; nt < 4; ++nt)
#pragma unroll
                for (int reg = 0; reg < 4; ++reg) {
                    const int m = m0 + wm * 64 + mt * 16 + quad * 4 + reg;
                    const int n = n0 + wn * 64 + nt * 16 + l16;
                    const int bb = m >> 11, tok = m & (SEQ - 1);
                    const int h = n >> 6, d = n & (HD - 1);
                    dst[(((size_t)bb * NHEAD + h) * SEQ + tok) * HD + d] =
                        f2bf(acc[mt][nt][reg] * qsc);
                }
    } else {
        // V^T epilogue: stage [d][m] in LDS (pad 136), then coalesced stores.
        const int bb = m0 >> 11, tok0 = m0 & (SEQ - 1);
#pragma unroll
        for (int pass = 0; pass < 2; ++pass) {
            __syncthreads();  // SM free (K-loop or previous pass done)
            if (wn == pass) {
#pragma unroll
                for (int mt = 0; mt < 4; ++mt)
#pragma unroll
                    for (int nt = 0; nt < 4; ++nt) {
                        const int d = nt * 16 + l16;
                        const int m = wm * 64 + mt * 16 + quad * 4;
                        uint2 w;
                        w.x = pk2bf(acc[mt][nt][0], acc[mt][nt][1]);
                        w.y = pk2bf(acc[mt][nt][2], acc[mt][nt][3]);
                        *(uint2*)&SM[d * 136 + m] = w;
                    }
            }
            __syncthreads();
            const int h = (n0 >> 6) + pass;
#pragma unroll
            for (int it = 0; it < 4; ++it) {
                const int c = it * 256 + tid;
                const int d = c >> 4, mc = (c & 15) * 8;
                uint4 val = *(const uint4*)&SM[d * 136 + mc];
                *(uint4*)(vt + (((size_t)bb * NHEAD + h) * HD + d) * SEQ + tok0 + mc) = val;
            }
        }
    }
}

// ---------------------------------------------------------------------------
// MFMA flash attention (causal) with cp.async-style K/V pipeline.
// Grid (NHEAD, 32, BATCH)  -> flat%8 = h%8: one head's K/V pinned to one XCD L2.
// Block 128 = 2 waves, both on the SAME 64-row q-tile (wave w: rows +32w)
//   -> identical kt range, K/V tiles shared via LDS.
// K double-buffered (2x8KB), V single-buffered (8KB), loads split between
// waves via global_load_lds (no VGPR cost). Sync per iteration:
//   own-wave s_waitcnt vmcnt(N) BEFORE s_barrier  => both waves' DMA complete
//   after the barrier; prefetched K(kt+1) stays in flight (vmcnt never 0
//   except the final V wait).
// ---------------------------------------------------------------------------
__global__ __launch_bounds__(128) void attn_mfma(const unsigned short* __restrict__ Q,
                                                 const unsigned short* __restrict__ K,
                                                 const unsigned short* __restrict__ VT,
                                                 unsigned short* __restrict__ ctx) {
    __shared__ unsigned short Kb[2][4096];  // [buf][64 rows x 64 d]
    __shared__ unsigned short Vb[4096];     // [64 d x 64 kcol] (V^T tile)
    __shared__ unsigned short Ps[64][72];   // rows [32w,32w+32) private to wave w
    const int tid = threadIdx.x;
    const int wave = tid >> 6, lane = tid & 63;
    const int quad = lane >> 4, l16 = lane & 15;
    const int h = blockIdx.x, p = blockIdx.y, b = blockIdx.z;
    const int row0 = p * 64 + wave * 32;
    const unsigned short* Qp = Q + ((size_t)b * NHEAD + h) * SEQ * HD;
    const unsigned short* Kp = K + ((size_t)b * NHEAD + h) * SEQ * HD;
    const unsigned short* Vp = VT + ((size_t)b * NHEAD + h) * HD * SEQ;
    unsigned short (*Pw)[72] = (unsigned short (*)[72])&Ps[wave * 32];

    bf16x8 bQ[2][2];  // Q as B-operand: [q-frag][ks]
#pragma unroll
    for (int f = 0; f < 2; ++f)
#pragma unroll
        for (int ks = 0; ks < 2; ++ks)
            bQ[f][ks] = *(const bf16x8*)(Qp +
                (size_t)(row0 + f * 16 + l16) * HD + ks * 32 + quad * 8);

    f32x4 o[4][2];    // O^T accumulators: [d-tile][q-frag]
    float ps[2] = {0.f, 0.f};
#pragma unroll
    for (int nt = 0; nt < 4; ++nt)
#pragma unroll
        for (int f = 0; f < 2; ++f)
            o[nt][f] = (f32x4){0.f, 0.f, 0.f, 0.f};

    const int ktmax = p;  // same for both waves (rows p*64 .. p*64+63)

    // prologue: K(0) -> Kb[0]; each wave loads 4 of the 8 1KB chunks
#pragma unroll
    for (int i = 0; i < 4; ++i) {
        const int c = wave * 4 + i;
        async16(&Kb[0][c * 512], Kp + c * 512 + lane * 8);
    }

    for (int kt = 0; kt <= ktmax; ++kt) {
        const int cur = kt & 1;
        BAR();  // B0: previous iteration's V reads done before V overwrite

        // issue V(kt) (4 chunks/wave), then K(kt+1) prefetch (4 chunks/wave)
#pragma unroll
        for (int i = 0; i < 4; ++i) {
            const int c = wave * 4 + i;
            const int d = 8 * c + (lane >> 3), col = (lane & 7) * 8;
            async16(&Vb[c * 512], Vp + (size_t)d * SEQ + kt * 64 + col);
        }
        if (kt < ktmax) {
#pragma unroll
            for (int i = 0; i < 4; ++i) {
                const int c = wave * 4 + i;
                async16(&Kb[cur ^ 1][c * 512],
                        Kp + (size_t)(kt + 1) * 4096 + c * 512 + lane * 8);
            }
            // outstanding: K(kt)=4 old, V(kt)=4, K(kt+1)=4 -> wait oldest 4
            asm volatile("s_waitcnt vmcnt(8)" ::: "memory");
        } else {
            // outstanding: K(kt)=4 old, V(kt)=4 -> wait oldest 4
            asm volatile("s_waitcnt vmcnt(4)" ::: "memory");
        }
        BAR();  // B1: both waves' K(kt) halves complete

        // ---- S^T = K Q^T from Kb[cur] ----
        f32x4 sT[4][2];
#pragma unroll
        for (int mt = 0; mt < 4; ++mt) {
            bf16x8 aK0 = *(const bf16x8*)&Kb[cur][(mt * 16 + l16) * 64 + quad * 8];
            bf16x8 aK1 = *(const bf16x8*)&Kb[cur][(mt * 16 + l16) * 64 + 32 + quad * 8];
#pragma unroll
            for (int f = 0; f < 2; ++f) {
                sT[mt][f] = __builtin_amdgcn_mfma_f32_16x16x32_bf16(
                    aK0, bQ[f][0], (f32x4){0.f, 0.f, 0.f, 0.f}, 0, 0, 0);
                sT[mt][f] = __builtin_amdgcn_mfma_f32_16x16x32_bf16(
                    aK1, bQ[f][1], sT[mt][f], 0, 0, 0);
            }
        }

        // ---- exp2 + causal mask + packed P write + row-sum ----
        const bool diag = (kt == ktmax);
#pragma unroll
        for (int mt = 0; mt < 4; ++mt)
#pragma unroll
            for (int f = 0; f < 2; ++f) {
                float pv[4];
#pragma unroll
                for (int reg = 0; reg < 4; ++reg)
                    pv[reg] = exp2f(sT[mt][f][reg]);
                if (diag) {
                    const int kb = kt * 64 + mt * 16 + quad * 4;
                    const int qg = row0 + f * 16 + l16;
#pragma unroll
                    for (int reg = 0; reg < 4; ++reg)
                        pv[reg] = (kb + reg > qg) ? 0.f : pv[reg];
                }
                ps[f] += (pv[0] + pv[1]) + (pv[2] + pv[3]);
                uint2 w;
                w.x = pk2bf(pv[0], pv[1]);
                w.y = pk2bf(pv[2], pv[3]);
                *(uint2*)&Pw[f * 16 + l16][mt * 16 + quad * 4] = w;
            }

        // P back in B-layout (wave-private rows; compiler handles lgkm)
        bf16x8 bP[2][2];
#pragma unroll
        for (int f = 0; f < 2; ++f)
#pragma unroll
            for (int ks = 0; ks < 2; ++ks)
                bP[f][ks] = *(const bf16x8*)&Pw[f * 16 + l16][ks * 32 + quad * 8];

        if (kt < ktmax) {
            // wait V(kt): leaves K(kt+1)=4 in flight
            asm volatile("s_waitcnt vmcnt(4)" ::: "memory");
        } else {
            asm volatile("s_waitcnt vmcnt(0)" ::: "memory");
        }
        BAR();  // B2: both waves' V(kt) halves complete

        // ---- O^T += V^T P^T from Vb ----
#pragma unroll
        for (int nt = 0; nt < 4; ++nt) {
            bf16x8 aV0 = *(const bf16x8*)&Vb[(nt * 16 + l16) * 64 + quad * 8];
            bf16x8 aV1 = *(const bf16x8*)&Vb[(nt * 16 + l16) * 64 + 32 + quad * 8];
#pragma unroll
            for (int f = 0; f < 2; ++f) {
                o[nt][f] = __builtin_amdgcn_mfma_f32_16x16x32_bf16(
                    aV0, bP[f][0], o[nt][f], 0, 0, 0);
                o[nt][f] = __builtin_amdgcn_mfma_f32_16x16x32_bf16(
                    aV1, bP[f][1], o[nt][f], 0, 0, 0);
            }
        }
    }

    // row-sum reduce across quads (q-row lives in l16; partials in quads)
    float inv[2];
#pragma unroll
    for (int f = 0; f < 2; ++f) {
        ps[f] += __shfl_xor(ps[f], 16);
        ps[f] += __shfl_xor(ps[f], 32);
        inv[f] = 1.f / ps[f];
    }

    // ctx store: token = row0 + f*16 + l16; cols consecutive -> packed 8B
#pragma unroll
    for (int nt = 0; nt < 4; ++nt)
#pragma unroll
        for (int f = 0; f < 2; ++f) {
            const int tok = row0 + f * 16 + l16;
            const int col = h * HD + nt * 16 + quad * 4;
            uint2 w;
            w.x = pk2bf(o[nt][f][0] * inv[f], o[nt][f][1] * inv[f]);
            w.y = pk2bf(o[nt][f][2] * inv[f], o[nt][f][3] * inv[f]);
            *(uint2*)(ctx + ((size_t)b * SEQ + tok) * D_MODEL + col) = w;
        }
}

extern "C" void kernel_launch(void* const* d_in, const int* in_sizes, int n_in,
                              void* d_out, int out_size, void* d_ws, size_t ws_size,
                              hipStream_t stream) {
    const float* x  = (const float*)d_in[0];
    const float* Wq = (const float*)d_in[1];
    const float* Wk = (const float*)d_in[2];
    const float* Wv = (const float*)d_in[3];
    const float* Wo = (const float*)d_in[4];
    float* out = (float*)d_out;

    unsigned short* ws = (unsigned short*)d_ws;
    const size_t T = (size_t)MTOT * D_MODEL;  // 4,194,304 elements
    unsigned short* xb  = ws;                 // [4096,1024] bf16
    unsigned short* Wt  = ws + T;             // 4 x [1024,1024] bf16 (W^T)
    unsigned short* q   = ws + 2 * T;         // [B,H,N,64]  (pre-scaled)
    unsigned short* k   = ws + 3 * T;         // [B,H,N,64]
    unsigned short* vt  = ws + 4 * T;         // [B,H,64,N]
    unsigned short* ctx = ws + 5 * T;         // [4096,1024]

    convert_x<<<dim3(MTOT * D_MODEL / 1024), dim3(256), 0, stream>>>(x, xb);
    transpose_w<<<dim3(32, 32, 4), dim3(32, 8), 0, stream>>>(Wq, Wk, Wv, Wo, Wt);

    gemm_mfma<0><<<dim3(8, 32, 3), dim3(256), 0, stream>>>(xb, Wt, q, k, vt, nullptr);

    attn_mfma<<<dim3(NHEAD, 32, BATCH), dim3(128), 0, stream>>>(q, k, vt, ctx);

    gemm_mfma<1><<<dim3(8, 32, 1), dim3(256), 0, stream>>>(ctx, Wt + 3 * (size_t)D_MODEL * D_MODEL,
                                                           nullptr, nullptr, nullptr, out);
}

// Round 8
// 228.211 us; speedup vs baseline: 1.1189x; 1.0085x over previous
//
#include <hip/hip_runtime.h>
#include <math.h>

#define D_MODEL 1024
#define NHEAD 16
#define HD 64
#define SEQ 2048
#define BATCH 2
#define MTOT (BATCH * SEQ)  // 4096

typedef __attribute__((ext_vector_type(8))) short bf16x8;
typedef __attribute__((ext_vector_type(4))) float f32x4;

__device__ __forceinline__ unsigned short f2bf(float f) {
    unsigned int u = __float_as_uint(f);
    u += 0x7FFF + ((u >> 16) & 1);  // round-to-nearest-even
    return (unsigned short)(u >> 16);
}

__device__ __forceinline__ unsigned int pk2bf(float a, float b) {
    return (unsigned int)f2bf(a) | ((unsigned int)f2bf(b) << 16);
}

// async global->LDS, 16B per lane. lds must be the wave-uniform chunk base:
// HW writes lane's 16B to base + lane*16 (guide §5 caveat).
__device__ __forceinline__ void async16(unsigned short* lds, const unsigned short* g) {
    __builtin_amdgcn_global_load_lds(
        (const __attribute__((address_space(1))) unsigned int*)g,
        (__attribute__((address_space(3))) unsigned int*)lds, 16, 0, 0);
}

// raw barrier: no compiler-forced vmcnt(0) drain (unlike __syncthreads);
// "memory" clobber = compile-time fence so LDS/DMA ops don't cross.
#define BAR() asm volatile("s_barrier" ::: "memory")

// ---------------------------------------------------------------------------
// x (fp32 [4096,1024]) -> bf16, same layout.
// ---------------------------------------------------------------------------
__global__ __launch_bounds__(256) void convert_x(const float* __restrict__ x,
                                                 unsigned short* __restrict__ xb) {
    const int i = (blockIdx.x * 256 + threadIdx.x) * 4;
    float4 v = *(const float4*)(x + i);
    uint2 p;
    p.x = pk2bf(v.x, v.y);
    p.y = pk2bf(v.z, v.w);
    *(uint2*)(xb + i) = p;
}

// ---------------------------------------------------------------------------
// W [1024(k),1024(n)] fp32 -> Wt [1024(n),1024(k)] bf16, all 4 weights.
// ---------------------------------------------------------------------------
__global__ __launch_bounds__(256) void transpose_w(const float* __restrict__ W0,
                                                   const float* __restrict__ W1,
                                                   const float* __restrict__ W2,
                                                   const float* __restrict__ W3,
                                                   unsigned short* __restrict__ Wt) {
    __shared__ float T[32][33];
    const float* W = (blockIdx.z == 0) ? W0 : (blockIdx.z == 1) ? W1
                    : (blockIdx.z == 2) ? W2 : W3;
    unsigned short* out = Wt + (size_t)blockIdx.z * D_MODEL * D_MODEL;
    const int n0 = blockIdx.x * 32, k0 = blockIdx.y * 32;
    const int tx = threadIdx.x, ty = threadIdx.y;
#pragma unroll
    for (int i = 0; i < 4; ++i)
        T[ty + 8 * i][tx] = W[(size_t)(k0 + ty + 8 * i) * D_MODEL + n0 + tx];
    __syncthreads();
#pragma unroll
    for (int i = 0; i < 4; ++i)
        out[(size_t)(n0 + ty + 8 * i) * D_MODEL + k0 + tx] = f2bf(T[tx][ty + 8 * i]);
}

// ---------------------------------------------------------------------------
// bf16 MFMA GEMM, global_load_lds staging (width=16, unpadded LDS).
// 128x128 tile / block, BK=64, 256 threads = 4 waves (2x2), each wave 64x64.
// MODE 0: z selects Wq/Wk/Wv; writes Q (pre-scaled by 0.125*log2e), K ->
//         [B,H,N,64] and V -> V^T [B,H,64,N]; ALL epilogues LDS-staged with
//         fully-coalesced 16B stores.
// MODE 1: fp32 row-major output.
// ---------------------------------------------------------------------------
template <int MODE>
__global__ __launch_bounds__(256) void gemm_mfma(const unsigned short* __restrict__ A,
                                                 const unsigned short* __restrict__ Wt,
                                                 unsigned short* __restrict__ q,
                                                 unsigned short* __restrict__ k,
                                                 unsigned short* __restrict__ vt,
                                                 float* __restrict__ outf) {
    __shared__ unsigned short SM[16384];  // As = SM[0:8192), Bs = SM[8192:16384)
    const int tid = threadIdx.x;
    const int z = blockIdx.z;
    const unsigned short* B = Wt + (size_t)z * D_MODEL * D_MODEL;
    const int m0 = blockIdx.y * 128, n0 = blockIdx.x * 128;
    const int wave = tid >> 6, lane = tid & 63;
    const int quad = lane >> 4, l16 = lane & 15;
    const int wm = wave & 1, wn = wave >> 1;

    f32x4 acc[4][4];
#pragma unroll
    for (int mt = 0; mt < 4; ++mt)
#pragma unroll
        for (int nt = 0; nt < 4; ++nt)
            acc[mt][nt] = (f32x4){0.f, 0.f, 0.f, 0.f};

    for (int k0 = 0; k0 < D_MODEL; k0 += 64) {
        __syncthreads();  // previous iteration's reads done
#pragma unroll
        for (int i = 0; i < 4; ++i) {
            const int c = i * 256 + tid;
            const int r = c >> 3, cc = (c & 7) * 8;
            const int cbase = i * 256 + wave * 64;  // wave-uniform chunk base
            async16(SM + cbase * 8, A + (size_t)(m0 + r) * D_MODEL + k0 + cc);
            async16(SM + 8192 + cbase * 8, B + (size_t)(n0 + r) * D_MODEL + k0 + cc);
        }
        __syncthreads();  // drains vmcnt per barrier semantics
#pragma unroll
        for (int ks = 0; ks < 2; ++ks) {
            bf16x8 af[4], bfr[4];
#pragma unroll
            for (int mt = 0; mt < 4; ++mt)
                af[mt] = *(const bf16x8*)&SM[(wm * 64 + mt * 16 + l16) * 64 + ks * 32 + quad * 8];
#pragma unroll
            for (int nt = 0; nt < 4; ++nt)
                bfr[nt] = *(const bf16x8*)&SM[8192 + (wn * 64 + nt * 16 + l16) * 64 + ks * 32 + quad * 8];
#pragma unroll
            for (int mt = 0; mt < 4; ++mt)
#pragma unroll
                for (int nt = 0; nt < 4; ++nt)
                    acc[mt][nt] = __builtin_amdgcn_mfma_f32_16x16x32_bf16(
                        af[mt], bfr[nt], acc[mt][nt], 0, 0, 0);
        }
    }

    if (MODE == 1) {
#pragma unroll
        for (int mt = 0; mt < 4; ++mt)
#pragma unroll
            for (int nt = 0; nt < 4; ++nt)
#pragma unroll
                for (int reg = 0; reg < 4; ++reg) {
                    const int m = m0 + wm * 64 + mt * 16 + quad * 4 + reg;
                    const int n = n0 + wn * 64 + nt * 16 + l16;
                    outf[(size_t)m * D_MODEL + n] = acc[mt][nt][reg];
                }
    } else if (z < 2) {
        // Q/K epilogue: stage [tok][d] in LDS (2 heads side by side, row
        // stride 128), then fully-coalesced uint4 stores. 2 passes (wm).
        // Q gets softmax scale folded in (exp2 domain): 0.125 * log2(e).
        const float qsc = (z == 0) ? 0.18033688011112042f : 1.0f;
        unsigned short* dst = (z == 0) ? q : k;
        const int bb = m0 >> 11;
        const int tok0 = m0 & (SEQ - 1);
        const int h0 = n0 >> 6;  // 2 heads per 128-col tile
#pragma unroll
        for (int pass = 0; pass < 2; ++pass) {
            __syncthreads();  // SM free (K-loop or previous pass done)
            if (wm == pass) {
#pragma unroll
                for (int mt = 0; mt < 4; ++mt)
#pragma unroll
                    for (int nt = 0; nt < 4; ++nt)
#pragma unroll
                        for (int reg = 0; reg < 4; ++reg) {
                            const int r = mt * 16 + quad * 4 + reg;
                            const int cc = wn * 64 + nt * 16 + l16;
                            SM[r * 128 + cc] = f2bf(acc[mt][nt][reg] * qsc);
                        }
            }
            __syncthreads();
#pragma unroll
            for (int it = 0; it < 4; ++it) {
                const int cix = it * 256 + tid;
                const int r = cix >> 4, g = cix & 15;
                const int hh = g >> 3, d8 = g & 7;
                uint4 val = *(const uint4*)&SM[r * 128 + g * 8];
                *(uint4*)(dst + (((size_t)bb * NHEAD + h0 + hh) * SEQ +
                                 tok0 + pass * 64 + r) * HD + d8 * 8) = val;
            }
        }
    } else {
        // V^T epilogue: stage [d][m] in LDS (pad 136), then coalesced stores.
        const int bb = m0 >> 11, tok0 = m0 & (SEQ - 1);
#pragma unroll
        for (int pass = 0; pass < 2; ++pass) {
            __syncthreads();  // SM free (K-loop or previous pass done)
            if (wn == pass) {
#pragma unroll
                for (int mt = 0; mt < 4; ++mt)
#pragma unroll
                    for (int nt = 0; nt < 4; ++nt) {
                        const int d = nt * 16 + l16;
                        const int m = wm * 64 + mt * 16 + quad * 4;
                        uint2 w;
                        w.x = pk2bf(acc[mt][nt][0], acc[mt][nt][1]);
                        w.y = pk2bf(acc[mt][nt][2], acc[mt][nt][3]);
                        *(uint2*)&SM[d * 136 + m] = w;
                    }
            }
            __syncthreads();
            const int h = (n0 >> 6) + pass;
#pragma unroll
            for (int it = 0; it < 4; ++it) {
                const int c = it * 256 + tid;
                const int d = c >> 4, mc = (c & 15) * 8;
                uint4 val = *(const uint4*)&SM[d * 136 + mc];
                *(uint4*)(vt + (((size_t)bb * NHEAD + h) * HD + d) * SEQ + tok0 + mc) = val;
            }
        }
    }
}

// ---------------------------------------------------------------------------
// MFMA flash attention (causal) with cp.async-style K/V pipeline.
// Grid (NHEAD, 32, BATCH) -> flat%8 = h%8: one head's K/V pinned to one XCD L2.
// Block 128 = 2 waves on the SAME 64-row q-tile; K dbuf, V single buf,
// DMA split between waves; own-wave vmcnt waits before raw s_barrier.
// LDS layout of Kb/Vb is XOR-swizzled in 16B granules:
//   physical_granule = logical_granule ^ (row & 7)
// applied on BOTH the DMA source address (permutation within each 128B row,
// coalescing preserved) and the ds_read fragment address. Kills the 16-way
// bank conflicts of the unpadded [64][64] layout (R7: 8.1e6 conflict cycles).
// ---------------------------------------------------------------------------
__global__ __launch_bounds__(128) void attn_mfma(const unsigned short* __restrict__ Q,
                                                 const unsigned short* __restrict__ K,
                                                 const unsigned short* __restrict__ VT,
                                                 unsigned short* __restrict__ ctx) {
    __shared__ unsigned short Kb[2][4096];  // [buf][64 rows x 64 d] swizzled
    __shared__ unsigned short Vb[4096];     // [64 d x 64 kcol] swizzled
    __shared__ unsigned short Ps[64][72];   // rows [32w,32w+32) private to wave w
    const int tid = threadIdx.x;
    const int wave = tid >> 6, lane = tid & 63;
    const int quad = lane >> 4, l16 = lane & 15;
    const int h = blockIdx.x, p = blockIdx.y, b = blockIdx.z;
    const int row0 = p * 64 + wave * 32;
    const unsigned short* Qp = Q + ((size_t)b * NHEAD + h) * SEQ * HD;
    const unsigned short* Kp = K + ((size_t)b * NHEAD + h) * SEQ * HD;
    const unsigned short* Vp = VT + ((size_t)b * NHEAD + h) * HD * SEQ;
    unsigned short (*Pw)[72] = (unsigned short (*)[72])&Ps[wave * 32];

    // DMA swizzle: lane covers row (c*8 + lane>>3), physical granule lane&7;
    // source granule = (lane&7) ^ (lane>>3)
    const int srow = lane >> 3;
    const int sgr = ((lane & 7) ^ srow) * 8;

    bf16x8 bQ[2][2];  // Q as B-operand: [q-frag][ks]
#pragma unroll
    for (int f = 0; f < 2; ++f)
#pragma unroll
        for (int ks = 0; ks < 2; ++ks)
            bQ[f][ks] = *(const bf16x8*)(Qp +
                (size_t)(row0 + f * 16 + l16) * HD + ks * 32 + quad * 8);

    f32x4 o[4][2];    // O^T accumulators: [d-tile][q-frag]
    float ps[2] = {0.f, 0.f};
#pragma unroll
    for (int nt = 0; nt < 4; ++nt)
#pragma unroll
        for (int f = 0; f < 2; ++f)
            o[nt][f] = (f32x4){0.f, 0.f, 0.f, 0.f};

    const int ktmax = p;  // same for both waves (rows p*64 .. p*64+63)

    // prologue: K(0) -> Kb[0]; each wave loads 4 of the 8 1KB chunks
#pragma unroll
    for (int i = 0; i < 4; ++i) {
        const int c = wave * 4 + i;
        async16(&Kb[0][c * 512], Kp + (size_t)(c * 8 + srow) * HD + sgr);
    }

    for (int kt = 0; kt <= ktmax; ++kt) {
        const int cur = kt & 1;
        BAR();  // B0: previous iteration's V reads done before V overwrite

        // issue V(kt) (4 chunks/wave), then K(kt+1) prefetch (4 chunks/wave)
#pragma unroll
        for (int i = 0; i < 4; ++i) {
            const int c = wave * 4 + i;
            const int d = 8 * c + srow;
            async16(&Vb[c * 512], Vp + (size_t)d * SEQ + kt * 64 + sgr);
        }
        if (kt < ktmax) {
#pragma unroll
            for (int i = 0; i < 4; ++i) {
                const int c = wave * 4 + i;
                async16(&Kb[cur ^ 1][c * 512],
                        Kp + (size_t)((kt + 1) * 64 + c * 8 + srow) * HD + sgr);
            }
            // outstanding: K(kt)=4 old, V(kt)=4, K(kt+1)=4 -> wait oldest 4
            asm volatile("s_waitcnt vmcnt(8)" ::: "memory");
        } else {
            // outstanding: K(kt)=4 old, V(kt)=4 -> wait oldest 4
            asm volatile("s_waitcnt vmcnt(4)" ::: "memory");
        }
        BAR();  // B1: both waves' K(kt) halves complete

        // ---- S^T = K Q^T from Kb[cur] (swizzled reads) ----
        f32x4 sT[4][2];
#pragma unroll
        for (int mt = 0; mt < 4; ++mt) {
            const int krow = mt * 16 + l16;
            const int sw = (l16 & 7);
            bf16x8 aK0 = *(const bf16x8*)&Kb[cur][krow * 64 + ((0 + quad) ^ sw) * 8];
            bf16x8 aK1 = *(const bf16x8*)&Kb[cur][krow * 64 + ((4 + quad) ^ sw) * 8];
#pragma unroll
            for (int f = 0; f < 2; ++f) {
                sT[mt][f] = __builtin_amdgcn_mfma_f32_16x16x32_bf16(
                    aK0, bQ[f][0], (f32x4){0.f, 0.f, 0.f, 0.f}, 0, 0, 0);
                sT[mt][f] = __builtin_amdgcn_mfma_f32_16x16x32_bf16(
                    aK1, bQ[f][1], sT[mt][f], 0, 0, 0);
            }
        }

        // ---- exp2 + causal mask + packed P write + row-sum ----
        const bool diag = (kt == ktmax);
#pragma unroll
        for (int mt = 0; mt < 4; ++mt)
#pragma unroll
            for (int f = 0; f < 2; ++f) {
                float pv[4];
#pragma unroll
                for (int reg = 0; reg < 4; ++reg)
                    pv[reg] = exp2f(sT[mt][f][reg]);
                if (diag) {
                    const int kb = kt * 64 + mt * 16 + quad * 4;
                    const int qg = row0 + f * 16 + l16;
#pragma unroll
                    for (int reg = 0; reg < 4; ++reg)
                        pv[reg] = (kb + reg > qg) ? 0.f : pv[reg];
                }
                ps[f] += (pv[0] + pv[1]) + (pv[2] + pv[3]);
                uint2 w;
                w.x = pk2bf(pv[0], pv[1]);
                w.y = pk2bf(pv[2], pv[3]);
                *(uint2*)&Pw[f * 16 + l16][mt * 16 + quad * 4] = w;
            }

        // P back in B-layout (wave-private rows; compiler handles lgkm)
        bf16x8 bP[2][2];
#pragma unroll
        for (int f = 0; f < 2; ++f)
#pragma unroll
            for (int ks = 0; ks < 2; ++ks)
                bP[f][ks] = *(const bf16x8*)&Pw[f * 16 + l16][ks * 32 + quad * 8];

        if (kt < ktmax) {
            // wait V(kt): leaves K(kt+1)=4 in flight
            asm volatile("s_waitcnt vmcnt(4)" ::: "memory");
        } else {
            asm volatile("s_waitcnt vmcnt(0)" ::: "memory");
        }
        BAR();  // B2: both waves' V(kt) halves complete

        // ---- O^T += V^T P^T from Vb (swizzled reads) ----
#pragma unroll
        for (int nt = 0; nt < 4; ++nt) {
            const int drow = nt * 16 + l16;
            const int sw = (l16 & 7);
            bf16x8 aV0 = *(const bf16x8*)&Vb[drow * 64 + ((0 + quad) ^ sw) * 8];
            bf16x8 aV1 = *(const bf16x8*)&Vb[drow * 64 + ((4 + quad) ^ sw) * 8];
#pragma unroll
            for (int f = 0; f < 2; ++f) {
                o[nt][f] = __builtin_amdgcn_mfma_f32_16x16x32_bf16(
                    aV0, bP[f][0], o[nt][f], 0, 0, 0);
                o[nt][f] = __builtin_amdgcn_mfma_f32_16x16x32_bf16(
                    aV1, bP[f][1], o[nt][f], 0, 0, 0);
            }
        }
    }

    // row-sum reduce across quads (q-row lives in l16; partials in quads)
    float inv[2];
#pragma unroll
    for (int f = 0; f < 2; ++f) {
        ps[f] += __shfl_xor(ps[f], 16);
        ps[f] += __shfl_xor(ps[f], 32);
        inv[f] = 1.f / ps[f];
    }

    // ctx store: token = row0 + f*16 + l16; cols consecutive -> packed 8B
#pragma unroll
    for (int nt = 0; nt < 4; ++nt)
#pragma unroll
        for (int f = 0; f < 2; ++f) {
            const int tok = row0 + f * 16 + l16;
            const int col = h * HD + nt * 16 + quad * 4;
            uint2 w;
            w.x = pk2bf(o[nt][f][0] * inv[f], o[nt][f][1] * inv[f]);
            w.y = pk2bf(o[nt][f][2] * inv[f], o[nt][f][3] * inv[f]);
            *(uint2*)(ctx + ((size_t)b * SEQ + tok) * D_MODEL + col) = w;
        }
}

extern "C" void kernel_launch(void* const* d_in, const int* in_sizes, int n_in,
                              void* d_out, int out_size, void* d_ws, size_t ws_size,
                              hipStream_t stream) {
    const float* x  = (const float*)d_in[0];
    const float* Wq = (const float*)d_in[1];
    const float* Wk = (const float*)d_in[2];
    const float* Wv = (const float*)d_in[3];
    const float* Wo = (const float*)d_in[4];
    float* out = (float*)d_out;

    unsigned short* ws = (unsigned short*)d_ws;
    const size_t T = (size_t)MTOT * D_MODEL;  // 4,194,304 elements
    unsigned short* xb  = ws;                 // [4096,1024] bf16
    unsigned short* Wt  = ws + T;             // 4 x [1024,1024] bf16 (W^T)
    unsigned short* q   = ws + 2 * T;         // [B,H,N,64]  (pre-scaled)
    unsigned short* k   = ws + 3 * T;         // [B,H,N,64]
    unsigned short* vt  = ws + 4 * T;         // [B,H,64,N]
    unsigned short* ctx = ws + 5 * T;         // [4096,1024]

    convert_x<<<dim3(MTOT * D_MODEL / 1024), dim3(256), 0, stream>>>(x, xb);
    transpose_w<<<dim3(32, 32, 4), dim3(32, 8), 0, stream>>>(Wq, Wk, Wv, Wo, Wt);

    gemm_mfma<0><<<dim3(8, 32, 3), dim3(256), 0, stream>>>(xb, Wt, q, k, vt, nullptr);

    attn_mfma<<<dim3(NHEAD, 32, BATCH), dim3(128), 0, stream>>>(q, k, vt, ctx);

    gemm_mfma<1><<<dim3(8, 32, 1), dim3(256), 0, stream>>>(ctx, Wt + 3 * (size_t)D_MODEL * D_MODEL,
                                                           nullptr, nullptr, nullptr, out);
}